// Round 4
// baseline (110.221 us; speedup 1.0000x reference)
//
#include <hip/hip_runtime.h>
#include <math.h>

constexpr int B = 64, L = 2048, D = 1024, P = 512, C = 32;
constexpr int NT  = 256;
constexpr int CH1 = 64;                 // stage-1 K chunk
constexpr int NK  = 3072 / CH1;         // 48 k-chunks
constexpr int GRID = 4 * NK;            // 192 blocks (<= 256 CUs, co-resident)

// ws layout in floats
constexpr size_t OFF_P1  = 0;                          // partial1: NK*B*P
constexpr size_t OFF_C1  = (size_t)NK * B * P;         // c1: B*P
constexpr size_t OFF_C2  = OFF_C1 + (size_t)B * P;     // c2: B*P
constexpr size_t OFF_CTR = OFF_C2 + (size_t)B * P;     // 3 x u32
constexpr size_t WS_NEED_BYTES = OFF_CTR * 4 + 12;

__device__ __forceinline__ void bar_arrive(unsigned* ctr) {
    __syncthreads();                 // all block threads done with phase
    __threadfence();                 // publish global writes device-wide
    if (threadIdx.x == 0)
        __hip_atomic_fetch_add(ctr, 1u, __ATOMIC_RELEASE, __HIP_MEMORY_SCOPE_AGENT);
}
__device__ __forceinline__ void bar_wait(const unsigned* ctr, unsigned tgt) {
    if (threadIdx.x == 0) {
        while (__hip_atomic_load(ctr, __ATOMIC_ACQUIRE, __HIP_MEMORY_SCOPE_AGENT) < tgt)
            __builtin_amdgcn_s_sleep(2);
    }
    __syncthreads();
    __threadfence();
}

__global__ __launch_bounds__(NT) void relpred_onekernel(
    const float* __restrict__ enc, const int* __restrict__ prep_idx,
    const float* __restrict__ Wh, const float* __restrict__ Wp,
    const float* __restrict__ Wc, const float* __restrict__ Whid,
    const float* __restrict__ Wsc, float* __restrict__ out,
    float* __restrict__ ws)
{
    float* partial1 = ws + OFF_P1;
    float* c1g      = ws + OFF_C1;
    float* c2g      = ws + OFF_C2;
    unsigned* ctr   = (unsigned*)(ws + OFF_CTR);

    const int tid = threadIdx.x;
    const int bx  = blockIdx.x;

    // 50176 B shared, aliased across phases (phases separated by barriers)
    __shared__ __align__(16) float smem[64 * 68 + 64 * 128];

    // ================= P1: split-K stage-1 GEMM (all 192 blocks) =================
    {
        float* Xt = smem;             // [CH1][68] transposed X chunk (+pad)
        float* Wl = smem + 64 * 68;   // [CH1][128]
        const int ct   = bx & 3;      // col tile (128 cols)
        const int kc   = bx >> 2;     // k-chunk 0..47
        const int m    = kc >> 4;     // 0=head,1=prep,2=child (16 chunks each)
        const int koff = (kc & 15) * CH1;
        const float* Wm = (m == 0) ? Wh : (m == 1) ? Wp : Wc;

        for (int i = tid; i < CH1 * 32; i += NT) {
            const int r = i >> 5, c4 = (i & 31) * 4;
            *(float4*)&Wl[r * 128 + c4] =
                *(const float4*)&Wm[(size_t)(koff + r) * P + ct * 128 + c4];
        }
        for (int i = tid; i < 64 * 16; i += NT) {
            const int b = i >> 4, q = i & 15;
            const int row = prep_idx[b] + m - 1;
            const float4 v = *(const float4*)&enc[((size_t)b * L + row) * D + koff + q * 4];
            Xt[(q * 4 + 0) * 68 + b] = v.x; Xt[(q * 4 + 1) * 68 + b] = v.y;
            Xt[(q * 4 + 2) * 68 + b] = v.z; Xt[(q * 4 + 3) * 68 + b] = v.w;
        }
        __syncthreads();

        const int ty = tid >> 4, tx = tid & 15;
        float acc[4][8];
        #pragma unroll
        for (int i = 0; i < 4; ++i)
            #pragma unroll
            for (int j = 0; j < 8; ++j) acc[i][j] = 0.f;

        #pragma unroll 4
        for (int k = 0; k < CH1; ++k) {
            const float4 xv = *(float4*)&Xt[k * 68 + ty * 4];
            const float4 w0 = *(float4*)&Wl[k * 128 + tx * 8];
            const float4 w1 = *(float4*)&Wl[k * 128 + tx * 8 + 4];
            const float xs[4]  = {xv.x, xv.y, xv.z, xv.w};
            const float ws8[8] = {w0.x, w0.y, w0.z, w0.w, w1.x, w1.y, w1.z, w1.w};
            #pragma unroll
            for (int i = 0; i < 4; ++i)
                #pragma unroll
                for (int j = 0; j < 8; ++j) acc[i][j] += xs[i] * ws8[j];
        }
        #pragma unroll
        for (int i = 0; i < 4; ++i) {
            const int b = ty * 4 + i;
            const size_t base = ((size_t)kc * B + b) * P + ct * 128 + tx * 8;
            *(float4*)&partial1[base]     = make_float4(acc[i][0], acc[i][1], acc[i][2], acc[i][3]);
            *(float4*)&partial1[base + 4] = make_float4(acc[i][4], acc[i][5], acc[i][6], acc[i][7]);
        }
    }
    bar_arrive(&ctr[0]);
    if (bx >= 128) return;            // blocks 128..191 retire

    // ================= P2: reduce split-K + tanh -> c1 (blocks 0..127) ============
    {
        bar_wait(&ctr[0], GRID);
        const int o = bx * NT + tid;  // 128*256 = 32768 = B*P, o = b*512+p
        float s = 0.f;
        #pragma unroll 8
        for (int kc = 0; kc < NK; ++kc) s += partial1[(size_t)kc * (B * P) + o];
        c1g[o] = tanhf(s);
    }
    bar_arrive(&ctr[1]);
    if (bx >= 64) return;             // blocks 64..127 retire

    // ================= P3: c2 = tanh(c1 @ Whid), 8 q-cols per block (0..63) =======
    {
        bar_wait(&ctr[1], 128);
        float* Wt  = smem;                         // [512][8]  16 KB
        float* c1c = smem + 512 * 8;               // [64][68]  17.4 KB (padded)
        float* red = smem + 512 * 8 + 64 * 68;     // [64][4][8] 8 KB
        const int q0 = bx * 8;

        for (int i = tid; i < 1024; i += NT) {     // stage Whid column slice
            const int p = i >> 1, h = i & 1;
            *(float4*)&Wt[p * 8 + h * 4] =
                *(const float4*)&Whid[(size_t)p * P + q0 + h * 4];
        }
        const int b  = tid >> 2;      // 0..63
        const int ph = tid & 3;       // p-quarter within chunk
        float acc[8];
        #pragma unroll
        for (int j = 0; j < 8; ++j) acc[j] = 0.f;

        for (int cch = 0; cch < 8; ++cch) {        // 8 chunks of 64 p
            __syncthreads();                       // protect c1c reuse
            for (int i = tid; i < 64 * 16; i += NT) {
                const int r = i >> 4, c4 = (i & 15) * 4;
                *(float4*)&c1c[r * 68 + c4] =
                    *(const float4*)&c1g[r * 512 + cch * 64 + c4];
            }
            __syncthreads();
            #pragma unroll
            for (int pq = 0; pq < 4; ++pq) {
                const float4 cv = *(float4*)&c1c[b * 68 + ph * 16 + pq * 4];
                const float cs[4] = {cv.x, cv.y, cv.z, cv.w};
                #pragma unroll
                for (int pp = 0; pp < 4; ++pp) {
                    const int pgl = cch * 64 + ph * 16 + pq * 4 + pp;
                    const float4 w0 = *(float4*)&Wt[pgl * 8];
                    const float4 w1 = *(float4*)&Wt[pgl * 8 + 4];
                    acc[0] += cs[pp] * w0.x; acc[1] += cs[pp] * w0.y;
                    acc[2] += cs[pp] * w0.z; acc[3] += cs[pp] * w0.w;
                    acc[4] += cs[pp] * w1.x; acc[5] += cs[pp] * w1.y;
                    acc[6] += cs[pp] * w1.z; acc[7] += cs[pp] * w1.w;
                }
            }
        }
        __syncthreads();
        #pragma unroll
        for (int j = 0; j < 8; ++j) red[(b * 4 + ph) * 8 + j] = acc[j];
        __syncthreads();
        for (int o = tid; o < 512; o += NT) {
            const int bb = o >> 3, j = o & 7;
            const float s = red[(bb * 4 + 0) * 8 + j] + red[(bb * 4 + 1) * 8 + j]
                          + red[(bb * 4 + 2) * 8 + j] + red[(bb * 4 + 3) * 8 + j];
            c2g[(size_t)bb * P + q0 + j] = tanhf(s);
        }
    }
    bar_arrive(&ctr[2]);

    // ================= P4: scorer + softmax, one batch per block (0..63) ==========
    {
        bar_wait(&ctr[2], 64);
        float* sp = smem;             // [8][32]
        const int b = bx;
        const int c = tid & 31, g = tid >> 5;
        float partial = 0.f;
        #pragma unroll
        for (int k = 0; k < 64; ++k) {
            const int p = g * 64 + k;
            partial += c2g[(size_t)b * P + p] * Wsc[(size_t)p * C + c];
        }
        sp[g * 32 + c] = partial;
        __syncthreads();
        if (tid < C) {
            float score = 0.f;
            #pragma unroll
            for (int gq = 0; gq < 8; ++gq) score += sp[gq * 32 + tid];
            float m = score;
            #pragma unroll
            for (int off = 16; off; off >>= 1) m = fmaxf(m, __shfl_xor(m, off));
            const float e = expf(score - m);
            float s = e;
            #pragma unroll
            for (int off = 16; off; off >>= 1) s += __shfl_xor(s, off);
            out[b * C + tid] = e / s;
        }
    }
}

extern "C" void kernel_launch(void* const* d_in, const int* in_sizes, int n_in,
                              void* d_out, int out_size, void* d_ws, size_t ws_size,
                              hipStream_t stream) {
    const float* enc      = (const float*)d_in[0];
    const int*   prep_idx = (const int*)  d_in[1];
    const float* Wh       = (const float*)d_in[2];
    const float* Wp       = (const float*)d_in[3];
    const float* Wc       = (const float*)d_in[4];
    const float* Whid     = (const float*)d_in[5];
    const float* Wsc      = (const float*)d_in[6];
    float*       out      = (float*)d_out;
    float*       wsf      = (float*)d_ws;

    (void)in_sizes; (void)n_in; (void)out_size; (void)ws_size;

    // zero the 3 barrier counters (12 B) — the only state needing re-init per call
    hipMemsetAsync((char*)d_ws + OFF_CTR * 4, 0, 12, stream);

    relpred_onekernel<<<GRID, NT, 0, stream>>>(enc, prep_idx, Wh, Wp, Wc,
                                               Whid, Wsc, out, wsf);
}

// Round 5
// 30.062 us; speedup vs baseline: 3.6665x; 3.6665x over previous
//
#include <hip/hip_runtime.h>
#include <math.h>

constexpr int B = 64, L = 2048, D = 1024, P = 512, C = 32;
constexpr int CH1 = 64;                 // stage-1 K chunk
constexpr int NK  = 3072 / CH1;         // 48 k-chunks
constexpr int G1  = 4 * NK;             // 192 blocks

// ===================== K1: split-K stage-1 GEMM =====================
// partial1[kc][b][p] = X[b, k-chunk] dot W1[k-chunk, p]
// X = concat(head,prep,child) (64 x 3072), W1 = [Wh;Wp;Wc] (3072 x 512)
__global__ __launch_bounds__(256) void k1_stage1(
    const float* __restrict__ enc, const int* __restrict__ prep_idx,
    const float* __restrict__ Wh, const float* __restrict__ Wp,
    const float* __restrict__ Wc, float* __restrict__ partial1)
{
    const int tid = threadIdx.x;
    const int ct  = blockIdx.x & 3;            // col tile (128 cols)
    const int kc  = blockIdx.x >> 2;           // k-chunk 0..47
    const int m    = kc >> 4;                  // 0=head,1=prep,2=child
    const int koff = (kc & 15) * CH1;
    const float* Wm = (m == 0) ? Wh : (m == 1) ? Wp : Wc;

    __shared__ float Xt[CH1][68];              // transposed X chunk (+pad)
    __shared__ float Wl[CH1][128];

    // stage W chunk: 64 x 128, coalesced float4
    for (int i = tid; i < CH1 * 32; i += 256) {
        const int r = i >> 5, c4 = (i & 31) * 4;
        *(float4*)&Wl[r][c4] =
            *(const float4*)&Wm[(size_t)(koff + r) * P + ct * 128 + c4];
    }
    // stage X chunk (gather row prep+m-1 per batch), transposed
    for (int i = tid; i < 64 * 16; i += 256) {
        const int b = i >> 4, q = i & 15;
        const int row = prep_idx[b] + m - 1;
        const float4 v = *(const float4*)&enc[((size_t)b * L + row) * D + koff + q * 4];
        Xt[q*4+0][b] = v.x; Xt[q*4+1][b] = v.y;
        Xt[q*4+2][b] = v.z; Xt[q*4+3][b] = v.w;
    }
    __syncthreads();

    const int ty = tid >> 4, tx = tid & 15;    // 16 batch-groups x 16 col-groups
    float acc[4][8];
    #pragma unroll
    for (int i = 0; i < 4; ++i)
        #pragma unroll
        for (int j = 0; j < 8; ++j) acc[i][j] = 0.f;

    #pragma unroll 4
    for (int k = 0; k < CH1; ++k) {
        const float4 xv = *(float4*)&Xt[k][ty * 4];
        const float4 w0 = *(float4*)&Wl[k][tx * 8];
        const float4 w1 = *(float4*)&Wl[k][tx * 8 + 4];
        const float xs[4]  = {xv.x, xv.y, xv.z, xv.w};
        const float ws8[8] = {w0.x, w0.y, w0.z, w0.w, w1.x, w1.y, w1.z, w1.w};
        #pragma unroll
        for (int i = 0; i < 4; ++i)
            #pragma unroll
            for (int j = 0; j < 8; ++j) acc[i][j] += xs[i] * ws8[j];
    }

    #pragma unroll
    for (int i = 0; i < 4; ++i) {
        const int b = ty * 4 + i;
        const size_t base = ((size_t)kc * B + b) * P + ct * 128 + tx * 8;
        *(float4*)&partial1[base]     = make_float4(acc[i][0], acc[i][1], acc[i][2], acc[i][3]);
        *(float4*)&partial1[base + 4] = make_float4(acc[i][4], acc[i][5], acc[i][6], acc[i][7]);
    }
}

// ===================== K2: reduce + tanh + hidden + tanh + scorer + softmax =====
// One block per batch, 512 threads (one output column each).
__global__ __launch_bounds__(512) void k2_tail(
    const float* __restrict__ partial1, const float* __restrict__ Whid,
    const float* __restrict__ Wsc, float* __restrict__ out)
{
    const int b   = blockIdx.x;
    const int tid = threadIdx.x;

    __shared__ float c1[P];
    __shared__ float c2[P];
    __shared__ float sp[16][C];

    // reduce split-K partials + tanh -> c1 (thread tid owns column tid)
    {
        float s = 0.f;
        #pragma unroll 8
        for (int kc = 0; kc < NK; ++kc)
            s += partial1[((size_t)kc * B + b) * P + tid];
        c1[tid] = tanhf(s);
    }
    __syncthreads();

    // hidden GEMV: c2 = tanh(c1 @ Whid); thread owns column q = tid
    {
        float s = 0.f;
        #pragma unroll 8
        for (int p = 0; p < P; ++p)
            s += c1[p] * Whid[(size_t)p * P + tid];
        c2[tid] = tanhf(s);
    }
    __syncthreads();

    // scorer GEMV: 16 groups x 32 p's each, then reduce
    {
        const int c = tid & (C - 1);
        const int g = tid >> 5;                 // 0..15
        float partial = 0.f;
        #pragma unroll
        for (int k = 0; k < 32; ++k) {
            const int p = g * 32 + k;
            partial += c2[p] * Wsc[(size_t)p * C + c];
        }
        sp[g][c] = partial;
    }
    __syncthreads();

    if (tid < C) {
        float score = 0.f;
        #pragma unroll
        for (int gq = 0; gq < 16; ++gq) score += sp[gq][tid];
        float m = score;
        #pragma unroll
        for (int off = 16; off; off >>= 1) m = fmaxf(m, __shfl_xor(m, off));
        const float e = expf(score - m);
        float s = e;
        #pragma unroll
        for (int off = 16; off; off >>= 1) s += __shfl_xor(s, off);
        out[b * C + tid] = e / s;
    }
}

extern "C" void kernel_launch(void* const* d_in, const int* in_sizes, int n_in,
                              void* d_out, int out_size, void* d_ws, size_t ws_size,
                              hipStream_t stream) {
    const float* enc      = (const float*)d_in[0];
    const int*   prep_idx = (const int*)  d_in[1];
    const float* Wh       = (const float*)d_in[2];
    const float* Wp       = (const float*)d_in[3];
    const float* Wc       = (const float*)d_in[4];
    const float* Whid     = (const float*)d_in[5];
    const float* Wsc      = (const float*)d_in[6];
    float*       out      = (float*)d_out;
    float*       partial1 = (float*)d_ws;      // NK*B*P floats = 6.3 MB

    (void)in_sizes; (void)n_in; (void)out_size; (void)ws_size;

    k1_stage1<<<G1, 256, 0, stream>>>(enc, prep_idx, Wh, Wp, Wc, partial1);
    k2_tail<<<B, 512, 0, stream>>>(partial1, Whid, Wsc, out);
}